// Round 9
// baseline (518.372 us; speedup 1.0000x reference)
//
#include <hip/hip_runtime.h>
#include <hip/hip_bf16.h>
#include <hip/hip_fp16.h>

// Problem constants (match reference)
#define TT 64
#define GN 1024
#define DK 128
#define NN (TT * GN)      // 65536
#define OUTC 131          // 3 + 128
#define TAU 8e-3f         // rescue threshold, 14 sigma of fp16-induced sim error

typedef _Float16 f16x8 __attribute__((ext_vector_type(8)));
typedef float    f32x4 __attribute__((ext_vector_type(4)));

// fp32 -> fp16 round-to-nearest-even, as raw 16 bits
__device__ __forceinline__ unsigned f2h(float f) {
    return (unsigned)__half_as_ushort(__float2half(f));
}

// async global->LDS, 16 B per lane; LDS dest must be lane-contiguous (m104)
__device__ __forceinline__ void gload_lds16(const void* g, void* l) {
    __builtin_amdgcn_global_load_lds(
        (const __attribute__((address_space(1))) unsigned int*)g,
        (__attribute__((address_space(3))) unsigned int*)l, 16, 0, 0);
}

// ---------------------------------------------------------------------------
// Kernel 1: fused fp16 conversion + per-row reciprocal norms (fp64 accum).
// ---------------------------------------------------------------------------
__global__ void kconv(const float* __restrict__ feat, unsigned* __restrict__ fh,
                      float* __restrict__ rnf, double* __restrict__ rnd) {
    int row  = blockIdx.x * 4 + (threadIdx.x >> 6);
    int lane = threadIdx.x & 63;
    const float* fr = feat + (size_t)row * DK;
    float2 v = *(const float2*)(fr + lane * 2);
    fh[(size_t)row * 64 + lane] = f2h(v.x) | (f2h(v.y) << 16);
    double s = (double)v.x * (double)v.x + (double)v.y * (double)v.y;
    #pragma unroll
    for (int off = 32; off > 0; off >>= 1)
        s += __shfl_down(s, off);
    if (lane == 0) {
        double m = sqrt(s);
        if (m < 1e-6) m = 1e-6;
        double r = 1.0 / m;
        rnd[row] = r;
        rnf[row] = (float)r;
    }
}

// ---------------------------------------------------------------------------
// Kernel 2: 4032 independent 128x128x128 GEMM tile blocks (t, mt, nt).
// Stage A+B tiles (fp16, 32 KB each) via global_load_lds w/ source-side XOR
// granule swizzle; 4 waves, wave tile 64x64, 16x16x32 MFMA. Output: per-row
// top-2 over this block's 128 cols -> tws.
// ---------------------------------------------------------------------------
__global__ __launch_bounds__(256) void ksim(const unsigned* __restrict__ fh,
                                            const float* __restrict__ rnf,
                                            float4* __restrict__ tws) {
    __shared__ int Atile[8192];    // 128 rows x 16 granules (32 KB)
    __shared__ int Btile[8192];

    int id = blockIdx.x;           // t*64 + mt*8 + nt
    int t  = id >> 6;              // 0..62
    int mt = (id >> 3) & 7;
    int nt = id & 7;

    int tid  = threadIdx.x;
    int wave = tid >> 6;
    int lane = tid & 63;
    int la = lane & 15;
    int lq = lane >> 4;
    int wr = (wave & 1) * 64;      // wave row offset
    int wc = (wave >> 1) * 64;     // wave col offset

    const int* Ag = (const int*)fh + ((size_t)t * GN + mt * 128) * 64;
    const int* Bg = (const int*)fh + ((size_t)(t + 1) * GN + nt * 128) * 64;

    #pragma unroll
    for (int i = 0; i < 8; ++i) {
        int L = i * 256 + tid;         // granule index in tile
        int row = L >> 4, colL = L & 15;
        int colG = colL ^ (row & 7);
        gload_lds16(Ag + row * 64 + colG * 4, &Atile[L * 4]);
        gload_lds16(Bg + row * 64 + colG * 4, &Btile[L * 4]);
    }
    __syncthreads();                   // includes vmcnt(0) drain

    f32x4 acc[4][4];
    #pragma unroll
    for (int at = 0; at < 4; ++at)
        #pragma unroll
        for (int ct = 0; ct < 4; ++ct) acc[at][ct] = (f32x4){0.f, 0.f, 0.f, 0.f};

    #pragma unroll
    for (int kc = 0; kc < 4; ++kc) {
        int sw = ((kc * 4 + lq) ^ (la & 7)) << 2;   // swizzled in-row int offset
        f16x8 af[4], bf[4];
        #pragma unroll
        for (int x = 0; x < 4; ++x) {
            af[x] = __builtin_bit_cast(f16x8, *(const int4*)&Atile[(wr + x * 16 + la) * 64 + sw]);
            bf[x] = __builtin_bit_cast(f16x8, *(const int4*)&Btile[(wc + x * 16 + la) * 64 + sw]);
        }
        #pragma unroll
        for (int at = 0; at < 4; ++at)
            #pragma unroll
            for (int ct = 0; ct < 4; ++ct)
                acc[at][ct] = __builtin_amdgcn_mfma_f32_16x16x32_f16(
                    af[at], bf[ct], acc[at][ct], 0, 0, 0);
    }

    // per-lane top-2 over this block's cols (C layout: col=la, row=lq*4+reg)
    float t1[16], t2[16]; int i1[16];
    #pragma unroll
    for (int s = 0; s < 16; ++s) { t1[s] = -3.4e38f; t2[s] = -3.4e38f; i1[s] = 0x7fffffff; }

    const float* rB = rnf + (size_t)(t + 1) * GN + nt * 128;
    #pragma unroll
    for (int ct = 0; ct < 4; ++ct) {               // ct ascending = n ascending
        int cloc = wc + ct * 16 + la;
        int n = nt * 128 + cloc;
        float rn = rB[cloc];
        #pragma unroll
        for (int at = 0; at < 4; ++at) {
            #pragma unroll
            for (int reg = 0; reg < 4; ++reg) {
                float v = acc[at][ct][reg] * rn;
                int s = at * 4 + reg;
                t2[s] = fmaxf(t2[s], fminf(v, t1[s]));   // med3(v,t1,t2)
                if (v > t1[s]) { t1[s] = v; i1[s] = n; }
            }
        }
    }

    // butterfly top-2 merge over the 16 la-lanes (same lq group)
    #pragma unroll
    for (int m = 1; m <= 8; m <<= 1) {
        #pragma unroll
        for (int s = 0; s < 16; ++s) {
            float o1 = __shfl_xor(t1[s], m);
            float o2 = __shfl_xor(t2[s], m);
            int   oi = __shfl_xor(i1[s], m);
            bool take = (o1 > t1[s]) || (o1 == t1[s] && oi < i1[s]);
            float nt2 = take ? fmaxf(o2, t1[s]) : fmaxf(t2[s], o1);
            if (take) { t1[s] = o1; i1[s] = oi; }
            t2[s] = nt2;
        }
    }

    // cross-wave merge (2 column halves) via overlay on Atile
    __syncthreads();                   // all tile reads done
    float* mv1 = (float*)Atile;        // [128][2]
    float* mv2 = mv1 + 256;
    int*   mi1 = (int*)(mv2 + 256);
    if (la == 0) {
        #pragma unroll
        for (int s = 0; s < 16; ++s) {
            int row = wr + (s >> 2) * 16 + lq * 4 + (s & 3);
            int idx = row * 2 + (wave >> 1);
            mv1[idx] = t1[s]; mv2[idx] = t2[s]; mi1[idx] = i1[s];
        }
    }
    __syncthreads();

    if (tid < 128) {
        float best = mv1[tid * 2], sec, bw2 = mv2[tid * 2];
        int bi = mi1[tid * 2];
        float v1 = mv1[tid * 2 + 1], v2 = mv2[tid * 2 + 1];
        int  ii = mi1[tid * 2 + 1];
        if (v1 > best || (v1 == best && ii < bi)) {
            sec = fmaxf(best, v2); best = v1; bi = ii;   // winner half 1
        } else {
            sec = fmaxf(v1, bw2);
        }
        float4 o; o.x = best; o.y = sec; o.z = __int_as_float(bi); o.w = 0.f;
        tws[((size_t)t * GN + mt * 128 + tid) * 8 + nt] = o;
    }
}

// ---------------------------------------------------------------------------
// Kernel 3: merge 8 colblock candidates per row; gap<TAU -> rescue list.
// Emits nxt16 (ushort local col index in next group).
// ---------------------------------------------------------------------------
__global__ void kmerge(const float4* __restrict__ tws, unsigned short* __restrict__ nxt16,
                       int* __restrict__ rcount, int* __restrict__ rlist) {
    int idx = blockIdx.x * 256 + threadIdx.x;      // 0..64511
    const float4* e = tws + (size_t)idx * 8;
    float best = -3.4e38f, sec = -3.4e38f, bw2 = -3.4e38f;
    int bi = 0x7fffffff;
    #pragma unroll
    for (int nb = 0; nb < 8; ++nb) {               // nb ascending = n ascending
        float4 v = e[nb];
        int ii = __float_as_int(v.z);
        if (v.x > best || (v.x == best && ii < bi)) {
            sec = fmaxf(sec, best);
            best = v.x; bi = ii; bw2 = v.y;
        } else {
            sec = fmaxf(sec, v.x);
        }
    }
    sec = fmaxf(sec, bw2);
    if (best - sec < TAU) {
        int p = atomicAdd(rcount, 1);
        rlist[p] = idx;
    } else {
        nxt16[idx] = (unsigned short)bi;
    }
}

// ---------------------------------------------------------------------------
// Kernel 4: fp64 rescue (exact: same math/tie rules as rounds 1-8).
// ---------------------------------------------------------------------------
__global__ void krescue(const float* __restrict__ feat, const double* __restrict__ rnd,
                        const int* __restrict__ rcount, const int* __restrict__ rlist,
                        unsigned short* __restrict__ nxt16) {
    __shared__ double sv[4];
    __shared__ int    si[4];
    int nr = *rcount;
    int tid = threadIdx.x, lane = tid & 63, wave = tid >> 6;
    for (int fi = blockIdx.x; fi < nr; fi += gridDim.x) {
        int idx = rlist[fi];
        int t = idx >> 10, grow = idx & 1023;
        const float* Arow = feat + ((size_t)t * GN + grow) * DK;
        const float* Bf   = feat + (size_t)(t + 1) * GN * DK;
        double bv = -1e300; int bi = 0x7fffffff;
        #pragma unroll
        for (int j = 0; j < 4; ++j) {
            int h = j * 256 + tid;
            const float* Brow = Bf + (size_t)h * DK;
            double s = 0.0;
            #pragma unroll 8
            for (int k = 0; k < DK; k += 4) {
                float4 a = *(const float4*)(Arow + k);
                float4 b = *(const float4*)(Brow + k);
                s = fma((double)a.x, (double)b.x, s);
                s = fma((double)a.y, (double)b.y, s);
                s = fma((double)a.z, (double)b.z, s);
                s = fma((double)a.w, (double)b.w, s);
            }
            s *= rnd[(t + 1) * GN + h];
            if (s > bv || (s == bv && h < bi)) { bv = s; bi = h; }
        }
        #pragma unroll
        for (int off = 32; off > 0; off >>= 1) {
            double ov = __shfl_down(bv, off);
            int    oi = __shfl_down(bi, off);
            if (ov > bv || (ov == bv && oi < bi)) { bv = ov; bi = oi; }
        }
        if (lane == 0) { sv[wave] = bv; si[wave] = bi; }
        __syncthreads();
        if (tid == 0) {
            double b2 = sv[0]; int i2 = si[0];
            #pragma unroll
            for (int w = 1; w < 4; ++w)
                if (sv[w] > b2 || (sv[w] == b2 && si[w] < i2)) { b2 = sv[w]; i2 = si[w]; }
            nxt16[idx] = (unsigned short)i2;
        }
        __syncthreads();
    }
}

// ---------------------------------------------------------------------------
// Kernel 5: chain propagation, fully LDS-resident. Single block, 1024 thr.
// nxt16 staged once into LDS; consumed slots recycled to hold chain ids;
// bulk coalesced flush at the end. Winner = min chain id (ids unique per
// contest, so min-on-id == the packed min of rounds 5-8).
// ---------------------------------------------------------------------------
__global__ __launch_bounds__(1024) void kgraph(const unsigned short* __restrict__ nxt16,
                                               int* __restrict__ chain_of) {
    __shared__ unsigned short ns[64 * 1024];   // 128 KB (slot 63 unused pad)
    __shared__ int winner[2 * 1024];           // 8 KB double-buffer
    int g = threadIdx.x;                       // 0..1023

    // stage all edges: 8 async rounds x 1024 lanes x 16 B = 128 KB
    #pragma unroll
    for (int i = 0; i < 8; ++i)
        gload_lds16((const char*)nxt16 + ((size_t)i * 1024 + g) * 16,
                    (char*)ns + ((size_t)i * 1024 + g) * 16);

    winner[g] = 0x7fffffff;
    chain_of[g] = g;                           // group 0: identity
    int mychain = g;
    __syncthreads();                           // drains the global_load_lds too

    for (int t = 0; t < TT - 1; ++t) {
        int* Wa = winner + (t & 1) * GN;
        int* Wb = winner + ((t + 1) & 1) * GN;
        int j = ns[t * GN + g];                // local index in group t+1
        atomicMin(&Wa[j], mychain);
        Wb[g] = 0x7fffffff;
        __syncthreads();
        int w = Wa[g];
        mychain = (w == 0x7fffffff) ? (((t + 1) << 10) | g) : w;
        ns[t * GN + g] = (unsigned short)mychain;   // recycle consumed slot
        __syncthreads();
    }

    // coalesced flush: groups 1..63
    for (int t = 0; t < TT - 1; ++t)
        chain_of[(t + 1) * GN + g] = ns[t * GN + g];
}

// ---------------------------------------------------------------------------
// Kernel 6: chain lengths by owner count (clen pre-zeroed via memsetAsync).
// ---------------------------------------------------------------------------
__global__ void kclen(const int* __restrict__ chain_of, int* __restrict__ clen) {
    int i = blockIdx.x * 256 + threadIdx.x;
    atomicAdd(&clen[chain_of[i]], 1);
}

// ---------------------------------------------------------------------------
// Kernel 7: exclusive prefix sum over kept chain lengths + total. One block.
// ---------------------------------------------------------------------------
__global__ void kscan(const int* __restrict__ chain_of, const int* __restrict__ clen,
                      const int* __restrict__ minp, int* __restrict__ offset,
                      int* __restrict__ total) {
    __shared__ int psum[1024];
    int tid = threadIdx.x;
    int ml  = *minp;
    int base = tid * 64;
    int local = 0;
    for (int e = 0; e < 64; ++e) {
        int s = base + e;
        if (chain_of[s] == s) { int cl = clen[s]; if (cl >= ml) local += cl; }
    }
    psum[tid] = local;
    __syncthreads();
    for (int off = 1; off < 1024; off <<= 1) {
        int add = (tid >= off) ? psum[tid - off] : 0;
        __syncthreads();
        psum[tid] += add;
        __syncthreads();
    }
    int run = tid ? psum[tid - 1] : 0;
    for (int e = 0; e < 64; ++e) {
        int s = base + e;
        int v = 0;
        if (chain_of[s] == s) { int cl = clen[s]; if (cl >= ml) v = cl; }
        offset[s] = run;
        run += v;
    }
    if (tid == 1023) *total = run;
}

// ---------------------------------------------------------------------------
// Kernel 8: zero only the non-kept tail of the output.
// ---------------------------------------------------------------------------
__global__ void kzero(const int* __restrict__ total, float* __restrict__ out) {
    long start = (long)(*total) * OUTC;
    long end   = (long)NN * OUTC;
    long gid   = (long)blockIdx.x * 256 + threadIdx.x;
    long stride = (long)gridDim.x * 256;
    for (long i = start + gid; i < end; i += stride) out[i] = 0.f;
}

// ---------------------------------------------------------------------------
// Kernel 9: scatter kept rows, one wave per node (4 nodes / 256-thr block).
// ---------------------------------------------------------------------------
__global__ void kscatter(const float* __restrict__ coor, const float* __restrict__ feat,
                         const int* __restrict__ chain_of, const int* __restrict__ clen,
                         const int* __restrict__ offset, const int* __restrict__ minp,
                         float* __restrict__ out) {
    int node = blockIdx.x * 4 + (threadIdx.x >> 6);
    int lane = threadIdx.x & 63;
    int s = chain_of[node];
    if (clen[s] < *minp) return;
    int row = offset[s] + (node >> 10) - (s >> 10);
    float* orow = out + (size_t)row * OUTC;
    const float* f = feat + (size_t)node * DK;
    if (lane < 3) orow[lane] = coor[(size_t)node * 3 + lane];
    orow[3 + lane]  = f[lane];
    orow[67 + lane] = f[64 + lane];
}

// ---------------------------------------------------------------------------
extern "C" void kernel_launch(void* const* d_in, const int* in_sizes, int n_in,
                              void* d_out, int out_size, void* d_ws, size_t ws_size,
                              hipStream_t stream) {
    const float* coor   = (const float*)d_in[0];   // [N,3]
    const float* feat   = (const float*)d_in[1];   // [N,128]
    const int*   minlen = (const int*)d_in[2];     // scalar
    float*       out    = (float*)d_out;           // [N,131] fp32

    char* ws = (char*)d_ws;
    double*         rnd      = (double*)(ws);                  // 512 KB
    float*          rnf      = (float*)(ws + 524288);          // 256 KB
    unsigned short* nxt16    = (unsigned short*)(ws + 786432); // 128 KB (64K entries, padded)
    int*            chain_of = (int*)(ws + 917504);            // 256 KB
    int*            clen     = (int*)(ws + 1179648);           // 256 KB
    int*            offset   = (int*)(ws + 1441792);           // 256 KB
    int*            total    = (int*)(ws + 1703936);
    int*            rcount   = (int*)(ws + 1704192);
    int*            rlist    = (int*)(ws + 1704448);           // 252 KB worst case
    unsigned*       fh       = (unsigned*)(ws + 2097152);      // 16 MB
    float4*         tws      = (float4*)(ws + 18874368);       // 8.25 MB

    hipMemsetAsync(rcount, 0, 4, stream);
    hipMemsetAsync(clen, 0, (size_t)NN * 4, stream);

    kconv<<<NN / 4, 256, 0, stream>>>(feat, fh, rnf, rnd);

    ksim<<<63 * 64, 256, 0, stream>>>(fh, rnf, tws);

    kmerge<<<63 * GN / 256, 256, 0, stream>>>(tws, nxt16, rcount, rlist);
    krescue<<<512, 256, 0, stream>>>(feat, rnd, rcount, rlist, nxt16);

    kgraph<<<1, GN, 0, stream>>>(nxt16, chain_of);
    kclen<<<NN / 256, 256, 0, stream>>>(chain_of, clen);
    kscan<<<1, GN, 0, stream>>>(chain_of, clen, minlen, offset, total);
    kzero<<<2048, 256, 0, stream>>>(total, out);
    kscatter<<<NN / 4, 256, 0, stream>>>(coor, feat, chain_of, clen, offset, minlen, out);
}

// Round 10
// 374.810 us; speedup vs baseline: 1.3830x; 1.3830x over previous
//
#include <hip/hip_runtime.h>
#include <hip/hip_bf16.h>
#include <hip/hip_fp16.h>

// Problem constants (match reference)
#define TT 64
#define GN 1024
#define DK 128
#define NN (TT * GN)      // 65536
#define OUTC 131          // 3 + 128
#define TAU 8e-3f         // rescue threshold, 14 sigma of fp16-induced sim error

typedef _Float16 f16x8 __attribute__((ext_vector_type(8)));
typedef float    f32x4 __attribute__((ext_vector_type(4)));

// fp32 -> fp16 round-to-nearest-even, as raw 16 bits
__device__ __forceinline__ unsigned f2h(float f) {
    return (unsigned)__half_as_ushort(__float2half(f));
}

// async global->LDS, 16 B per lane; LDS dest must be lane-contiguous (m104)
__device__ __forceinline__ void gload_lds16(const void* g, void* l) {
    __builtin_amdgcn_global_load_lds(
        (const __attribute__((address_space(1))) unsigned int*)g,
        (__attribute__((address_space(3))) unsigned int*)l, 16, 0, 0);
}

// ---------------------------------------------------------------------------
// Kernel 1: fused fp16 conversion + per-row reciprocal norms (fp64 accum).
// ---------------------------------------------------------------------------
__global__ void kconv(const float* __restrict__ feat, unsigned* __restrict__ fh,
                      float* __restrict__ rnf, double* __restrict__ rnd) {
    int row  = blockIdx.x * 4 + (threadIdx.x >> 6);
    int lane = threadIdx.x & 63;
    const float* fr = feat + (size_t)row * DK;
    float2 v = *(const float2*)(fr + lane * 2);
    fh[(size_t)row * 64 + lane] = f2h(v.x) | (f2h(v.y) << 16);
    double s = (double)v.x * (double)v.x + (double)v.y * (double)v.y;
    #pragma unroll
    for (int off = 32; off > 0; off >>= 1)
        s += __shfl_down(s, off);
    if (lane == 0) {
        double m = sqrt(s);
        if (m < 1e-6) m = 1e-6;
        double r = 1.0 / m;
        rnd[row] = r;
        rnf[row] = (float)r;
    }
}

// ---------------------------------------------------------------------------
// Kernel 2: 4032 independent 128x128x128 GEMM tile blocks (t, mt, nt).
// Stage A+B tiles (fp16, 32 KB each) via global_load_lds w/ source-side XOR
// granule swizzle; 4 waves, wave tile 64x64, 16x16x32 MFMA. Output: per-row
// top-2 over this block's 128 cols -> tws.
// ---------------------------------------------------------------------------
__global__ __launch_bounds__(256) void ksim(const unsigned* __restrict__ fh,
                                            const float* __restrict__ rnf,
                                            float4* __restrict__ tws) {
    __shared__ int Atile[8192];    // 128 rows x 16 granules (32 KB)
    __shared__ int Btile[8192];

    int id = blockIdx.x;           // t*64 + mt*8 + nt
    int t  = id >> 6;              // 0..62
    int mt = (id >> 3) & 7;
    int nt = id & 7;

    int tid  = threadIdx.x;
    int wave = tid >> 6;
    int lane = tid & 63;
    int la = lane & 15;
    int lq = lane >> 4;
    int wr = (wave & 1) * 64;      // wave row offset
    int wc = (wave >> 1) * 64;     // wave col offset

    const int* Ag = (const int*)fh + ((size_t)t * GN + mt * 128) * 64;
    const int* Bg = (const int*)fh + ((size_t)(t + 1) * GN + nt * 128) * 64;

    #pragma unroll
    for (int i = 0; i < 8; ++i) {
        int L = i * 256 + tid;         // granule index in tile
        int row = L >> 4, colL = L & 15;
        int colG = colL ^ (row & 7);
        gload_lds16(Ag + row * 64 + colG * 4, &Atile[L * 4]);
        gload_lds16(Bg + row * 64 + colG * 4, &Btile[L * 4]);
    }
    __syncthreads();                   // includes vmcnt(0) drain

    f32x4 acc[4][4];
    #pragma unroll
    for (int at = 0; at < 4; ++at)
        #pragma unroll
        for (int ct = 0; ct < 4; ++ct) acc[at][ct] = (f32x4){0.f, 0.f, 0.f, 0.f};

    #pragma unroll
    for (int kc = 0; kc < 4; ++kc) {
        int sw = ((kc * 4 + lq) ^ (la & 7)) << 2;   // swizzled in-row int offset
        f16x8 af[4], bf[4];
        #pragma unroll
        for (int x = 0; x < 4; ++x) {
            af[x] = __builtin_bit_cast(f16x8, *(const int4*)&Atile[(wr + x * 16 + la) * 64 + sw]);
            bf[x] = __builtin_bit_cast(f16x8, *(const int4*)&Btile[(wc + x * 16 + la) * 64 + sw]);
        }
        #pragma unroll
        for (int at = 0; at < 4; ++at)
            #pragma unroll
            for (int ct = 0; ct < 4; ++ct)
                acc[at][ct] = __builtin_amdgcn_mfma_f32_16x16x32_f16(
                    af[at], bf[ct], acc[at][ct], 0, 0, 0);
    }

    // per-lane top-2 over this block's cols (C layout: col=la, row=lq*4+reg)
    float t1[16], t2[16]; int i1[16];
    #pragma unroll
    for (int s = 0; s < 16; ++s) { t1[s] = -3.4e38f; t2[s] = -3.4e38f; i1[s] = 0x7fffffff; }

    const float* rB = rnf + (size_t)(t + 1) * GN + nt * 128;
    #pragma unroll
    for (int ct = 0; ct < 4; ++ct) {               // ct ascending = n ascending
        int cloc = wc + ct * 16 + la;
        int n = nt * 128 + cloc;
        float rn = rB[cloc];
        #pragma unroll
        for (int at = 0; at < 4; ++at) {
            #pragma unroll
            for (int reg = 0; reg < 4; ++reg) {
                float v = acc[at][ct][reg] * rn;
                int s = at * 4 + reg;
                t2[s] = fmaxf(t2[s], fminf(v, t1[s]));   // med3(v,t1,t2)
                if (v > t1[s]) { t1[s] = v; i1[s] = n; }
            }
        }
    }

    // butterfly top-2 merge over the 16 la-lanes (same lq group)
    #pragma unroll
    for (int m = 1; m <= 8; m <<= 1) {
        #pragma unroll
        for (int s = 0; s < 16; ++s) {
            float o1 = __shfl_xor(t1[s], m);
            float o2 = __shfl_xor(t2[s], m);
            int   oi = __shfl_xor(i1[s], m);
            bool take = (o1 > t1[s]) || (o1 == t1[s] && oi < i1[s]);
            float nt2 = take ? fmaxf(o2, t1[s]) : fmaxf(t2[s], o1);
            if (take) { t1[s] = o1; i1[s] = oi; }
            t2[s] = nt2;
        }
    }

    // cross-wave merge (2 column halves) via overlay on Atile
    __syncthreads();                   // all tile reads done
    float* mv1 = (float*)Atile;        // [128][2]
    float* mv2 = mv1 + 256;
    int*   mi1 = (int*)(mv2 + 256);
    if (la == 0) {
        #pragma unroll
        for (int s = 0; s < 16; ++s) {
            int row = wr + (s >> 2) * 16 + lq * 4 + (s & 3);
            int idx = row * 2 + (wave >> 1);
            mv1[idx] = t1[s]; mv2[idx] = t2[s]; mi1[idx] = i1[s];
        }
    }
    __syncthreads();

    if (tid < 128) {
        float best = mv1[tid * 2], sec, bw2 = mv2[tid * 2];
        int bi = mi1[tid * 2];
        float v1 = mv1[tid * 2 + 1], v2 = mv2[tid * 2 + 1];
        int  ii = mi1[tid * 2 + 1];
        if (v1 > best || (v1 == best && ii < bi)) {
            sec = fmaxf(best, v2); best = v1; bi = ii;   // winner half 1
        } else {
            sec = fmaxf(v1, bw2);
        }
        float4 o; o.x = best; o.y = sec; o.z = __int_as_float(bi); o.w = 0.f;
        tws[((size_t)t * GN + mt * 128 + tid) * 8 + nt] = o;
    }
}

// ---------------------------------------------------------------------------
// Kernel 3: merge 8 colblock candidates per row; gap<TAU -> rescue list.
// Emits nxt16 (ushort local col index in next group).
// ---------------------------------------------------------------------------
__global__ void kmerge(const float4* __restrict__ tws, unsigned short* __restrict__ nxt16,
                       int* __restrict__ rcount, int* __restrict__ rlist) {
    int idx = blockIdx.x * 256 + threadIdx.x;      // 0..64511
    const float4* e = tws + (size_t)idx * 8;
    float best = -3.4e38f, sec = -3.4e38f, bw2 = -3.4e38f;
    int bi = 0x7fffffff;
    #pragma unroll
    for (int nb = 0; nb < 8; ++nb) {               // nb ascending = n ascending
        float4 v = e[nb];
        int ii = __float_as_int(v.z);
        if (v.x > best || (v.x == best && ii < bi)) {
            sec = fmaxf(sec, best);
            best = v.x; bi = ii; bw2 = v.y;
        } else {
            sec = fmaxf(sec, v.x);
        }
    }
    sec = fmaxf(sec, bw2);
    if (best - sec < TAU) {
        int p = atomicAdd(rcount, 1);
        rlist[p] = idx;
    } else {
        nxt16[idx] = (unsigned short)bi;
    }
}

// ---------------------------------------------------------------------------
// Kernel 4: fp64 rescue (exact: same math/tie rules as rounds 1-9).
// ---------------------------------------------------------------------------
__global__ void krescue(const float* __restrict__ feat, const double* __restrict__ rnd,
                        const int* __restrict__ rcount, const int* __restrict__ rlist,
                        unsigned short* __restrict__ nxt16) {
    __shared__ double sv[4];
    __shared__ int    si[4];
    int nr = *rcount;
    int tid = threadIdx.x, lane = tid & 63, wave = tid >> 6;
    for (int fi = blockIdx.x; fi < nr; fi += gridDim.x) {
        int idx = rlist[fi];
        int t = idx >> 10, grow = idx & 1023;
        const float* Arow = feat + ((size_t)t * GN + grow) * DK;
        const float* Bf   = feat + (size_t)(t + 1) * GN * DK;
        double bv = -1e300; int bi = 0x7fffffff;
        #pragma unroll
        for (int j = 0; j < 4; ++j) {
            int h = j * 256 + tid;
            const float* Brow = Bf + (size_t)h * DK;
            double s = 0.0;
            #pragma unroll 8
            for (int k = 0; k < DK; k += 4) {
                float4 a = *(const float4*)(Arow + k);
                float4 b = *(const float4*)(Brow + k);
                s = fma((double)a.x, (double)b.x, s);
                s = fma((double)a.y, (double)b.y, s);
                s = fma((double)a.z, (double)b.z, s);
                s = fma((double)a.w, (double)b.w, s);
            }
            s *= rnd[(t + 1) * GN + h];
            if (s > bv || (s == bv && h < bi)) { bv = s; bi = h; }
        }
        #pragma unroll
        for (int off = 32; off > 0; off >>= 1) {
            double ov = __shfl_down(bv, off);
            int    oi = __shfl_down(bi, off);
            if (ov > bv || (ov == bv && oi < bi)) { bv = ov; bi = oi; }
        }
        if (lane == 0) { sv[wave] = bv; si[wave] = bi; }
        __syncthreads();
        if (tid == 0) {
            double b2 = sv[0]; int i2 = si[0];
            #pragma unroll
            for (int w = 1; w < 4; ++w)
                if (sv[w] > b2 || (sv[w] == b2 && si[w] < i2)) { b2 = sv[w]; i2 = si[w]; }
            nxt16[idx] = (unsigned short)i2;
        }
        __syncthreads();
    }
}

// ---------------------------------------------------------------------------
// Kernel 5: chain propagation, fully LDS-resident. Single block, 1024 thr.
// ---------------------------------------------------------------------------
__global__ __launch_bounds__(1024) void kgraph(const unsigned short* __restrict__ nxt16,
                                               int* __restrict__ chain_of) {
    __shared__ unsigned short ns[64 * 1024];   // 128 KB (row 63 unused pad)
    __shared__ int winner[2 * 1024];           // 8 KB double-buffer
    int g = threadIdx.x;                       // 0..1023

    #pragma unroll
    for (int i = 0; i < 8; ++i)
        gload_lds16((const char*)nxt16 + ((size_t)i * 1024 + g) * 16,
                    (char*)ns + ((size_t)i * 1024 + g) * 16);

    winner[g] = 0x7fffffff;
    chain_of[g] = g;                           // group 0: identity
    int mychain = g;
    __syncthreads();                           // drains the global_load_lds too

    for (int t = 0; t < TT - 1; ++t) {
        int* Wa = winner + (t & 1) * GN;
        int* Wb = winner + ((t + 1) & 1) * GN;
        int j = ns[t * GN + g];                // local index in group t+1
        atomicMin(&Wa[j], mychain);
        Wb[g] = 0x7fffffff;
        __syncthreads();
        int w = Wa[g];
        mychain = (w == 0x7fffffff) ? (((t + 1) << 10) | g) : w;
        ns[t * GN + g] = (unsigned short)mychain;   // recycle consumed slot
        __syncthreads();
    }

    for (int t = 0; t < TT - 1; ++t)
        chain_of[(t + 1) * GN + g] = ns[t * GN + g];
}

// ---------------------------------------------------------------------------
// Kernel 6: chain lengths by owner count (clen pre-zeroed via memsetAsync).
// ---------------------------------------------------------------------------
__global__ void kclen(const int* __restrict__ chain_of, int* __restrict__ clen) {
    int i = blockIdx.x * 256 + threadIdx.x;
    atomicAdd(&clen[chain_of[i]], 1);
}

// ---------------------------------------------------------------------------
// Kernel 7a: per-block (1024-elem, coalesced) exclusive scan of kept lengths.
// oloc[i] = exclusive prefix within block; partial[b] = block total.
// ---------------------------------------------------------------------------
__global__ __launch_bounds__(1024) void kseg(const int* __restrict__ chain_of,
                                             const int* __restrict__ clen,
                                             const int* __restrict__ minp,
                                             int* __restrict__ oloc,
                                             int* __restrict__ partial) {
    __shared__ int ps[1024];
    int b = blockIdx.x, tid = threadIdx.x;
    int i = b * 1024 + tid;
    int ml = *minp;
    int cl = clen[i];
    int v = (chain_of[i] == i && cl >= ml) ? cl : 0;
    ps[tid] = v;
    __syncthreads();
    for (int off = 1; off < 1024; off <<= 1) {
        int add = (tid >= off) ? ps[tid - off] : 0;
        __syncthreads();
        ps[tid] += add;
        __syncthreads();
    }
    oloc[i] = ps[tid] - v;              // exclusive within block
    if (tid == 1023) partial[b] = ps[tid];
}

// ---------------------------------------------------------------------------
// Kernel 7b: one wave scans the 64 block partials; emits pbase + total.
// ---------------------------------------------------------------------------
__global__ void kpart(const int* __restrict__ partial, int* __restrict__ pbase,
                      int* __restrict__ total) {
    int tid = threadIdx.x;              // 0..63
    int v = partial[tid];
    int acc = v;
    #pragma unroll
    for (int off = 1; off < 64; off <<= 1) {
        int o = __shfl_up(acc, off);
        if (tid >= off) acc += o;
    }
    pbase[tid] = acc - v;               // exclusive
    if (tid == 63) *total = acc;
}

// ---------------------------------------------------------------------------
// Kernel 8: zero only the non-kept tail of the output.
// ---------------------------------------------------------------------------
__global__ void kzero(const int* __restrict__ total, float* __restrict__ out) {
    long start = (long)(*total) * OUTC;
    long end   = (long)NN * OUTC;
    long gid   = (long)blockIdx.x * 256 + threadIdx.x;
    long stride = (long)gridDim.x * 256;
    for (long i = start + gid; i < end; i += stride) out[i] = 0.f;
}

// ---------------------------------------------------------------------------
// Kernel 9: scatter kept rows, one wave per node (4 nodes / 256-thr block).
// offset(s) = oloc[s] + pbase[group(s)].
// ---------------------------------------------------------------------------
__global__ void kscatter(const float* __restrict__ coor, const float* __restrict__ feat,
                         const int* __restrict__ chain_of, const int* __restrict__ clen,
                         const int* __restrict__ oloc, const int* __restrict__ pbase,
                         const int* __restrict__ minp, float* __restrict__ out) {
    int node = blockIdx.x * 4 + (threadIdx.x >> 6);
    int lane = threadIdx.x & 63;
    int s = chain_of[node];
    if (clen[s] < *minp) return;
    int row = oloc[s] + pbase[s >> 10] + (node >> 10) - (s >> 10);
    float* orow = out + (size_t)row * OUTC;
    const float* f = feat + (size_t)node * DK;
    if (lane < 3) orow[lane] = coor[(size_t)node * 3 + lane];
    orow[3 + lane]  = f[lane];
    orow[67 + lane] = f[64 + lane];
}

// ---------------------------------------------------------------------------
extern "C" void kernel_launch(void* const* d_in, const int* in_sizes, int n_in,
                              void* d_out, int out_size, void* d_ws, size_t ws_size,
                              hipStream_t stream) {
    const float* coor   = (const float*)d_in[0];   // [N,3]
    const float* feat   = (const float*)d_in[1];   // [N,128]
    const int*   minlen = (const int*)d_in[2];     // scalar
    float*       out    = (float*)d_out;           // [N,131] fp32

    char* ws = (char*)d_ws;
    double*         rnd      = (double*)(ws);                  // 512 KB
    float*          rnf      = (float*)(ws + 524288);          // 256 KB
    unsigned short* nxt16    = (unsigned short*)(ws + 786432); // 128 KB
    int*            chain_of = (int*)(ws + 917504);            // 256 KB
    int*            clen     = (int*)(ws + 1179648);           // 256 KB
    int*            oloc     = (int*)(ws + 1441792);           // 256 KB
    int*            total    = (int*)(ws + 1703936);
    int*            rcount   = (int*)(ws + 1704192);
    int*            partial  = (int*)(ws + 1704448);           // 256 B
    int*            pbase    = (int*)(ws + 1704704);           // 256 B
    int*            rlist    = (int*)(ws + 1705216);           // 252 KB worst case
    unsigned*       fh       = (unsigned*)(ws + 2097152);      // 16 MB
    float4*         tws      = (float4*)(ws + 18874368);       // 8.25 MB

    hipMemsetAsync(rcount, 0, 4, stream);
    hipMemsetAsync(clen, 0, (size_t)NN * 4, stream);

    kconv<<<NN / 4, 256, 0, stream>>>(feat, fh, rnf, rnd);

    ksim<<<63 * 64, 256, 0, stream>>>(fh, rnf, tws);

    kmerge<<<63 * GN / 256, 256, 0, stream>>>(tws, nxt16, rcount, rlist);
    krescue<<<512, 256, 0, stream>>>(feat, rnd, rcount, rlist, nxt16);

    kgraph<<<1, GN, 0, stream>>>(nxt16, chain_of);
    kclen<<<NN / 256, 256, 0, stream>>>(chain_of, clen);
    kseg<<<64, 1024, 0, stream>>>(chain_of, clen, minlen, oloc, partial);
    kpart<<<1, 64, 0, stream>>>(partial, pbase, total);
    kzero<<<2048, 256, 0, stream>>>(total, out);
    kscatter<<<NN / 4, 256, 0, stream>>>(coor, feat, chain_of, clen, oloc, pbase,
                                         minlen, out);
}

// Round 11
// 328.242 us; speedup vs baseline: 1.5792x; 1.1419x over previous
//
#include <hip/hip_runtime.h>
#include <hip/hip_bf16.h>
#include <hip/hip_fp16.h>

// Problem constants (match reference)
#define TT 64
#define GN 1024
#define DK 128
#define NN (TT * GN)      // 65536
#define OUTC 131          // 3 + 128
#define TAU 8e-3f         // rescue threshold, 14 sigma of fp16-induced sim error

typedef _Float16 f16x8 __attribute__((ext_vector_type(8)));
typedef float    f32x4 __attribute__((ext_vector_type(4)));

// fp32 -> fp16 round-to-nearest-even, as raw 16 bits
__device__ __forceinline__ unsigned f2h(float f) {
    return (unsigned)__half_as_ushort(__float2half(f));
}

// async global->LDS, 16 B per lane; LDS dest must be lane-contiguous (m104)
__device__ __forceinline__ void gload_lds16(const void* g, void* l) {
    __builtin_amdgcn_global_load_lds(
        (const __attribute__((address_space(1))) unsigned int*)g,
        (__attribute__((address_space(3))) unsigned int*)l, 16, 0, 0);
}

// ---------------------------------------------------------------------------
// Kernel 1: fused fp16 conversion + per-row reciprocal norms (fp64 accum).
// ---------------------------------------------------------------------------
__global__ void kconv(const float* __restrict__ feat, unsigned* __restrict__ fh,
                      float* __restrict__ rnf, double* __restrict__ rnd) {
    int row  = blockIdx.x * 4 + (threadIdx.x >> 6);
    int lane = threadIdx.x & 63;
    const float* fr = feat + (size_t)row * DK;
    float2 v = *(const float2*)(fr + lane * 2);
    fh[(size_t)row * 64 + lane] = f2h(v.x) | (f2h(v.y) << 16);
    double s = (double)v.x * (double)v.x + (double)v.y * (double)v.y;
    #pragma unroll
    for (int off = 32; off > 0; off >>= 1)
        s += __shfl_down(s, off);
    if (lane == 0) {
        double m = sqrt(s);
        if (m < 1e-6) m = 1e-6;
        double r = 1.0 / m;
        rnd[row] = r;
        rnf[row] = (float)r;
    }
}

// ---------------------------------------------------------------------------
// Kernel 2: 4032 independent 128x128x128 GEMM tile blocks (t, mt, nt).
// Stage A+B tiles (fp16, 32 KB each) via global_load_lds w/ source-side XOR
// granule swizzle; 4 waves, wave tile 64x64, 16x16x32 MFMA. Output: per-row
// top-2 over this block's 128 cols -> tws.
// ---------------------------------------------------------------------------
__global__ __launch_bounds__(256) void ksim(const unsigned* __restrict__ fh,
                                            const float* __restrict__ rnf,
                                            float4* __restrict__ tws) {
    __shared__ int Atile[8192];    // 128 rows x 16 granules (32 KB)
    __shared__ int Btile[8192];

    int id = blockIdx.x;           // t*64 + mt*8 + nt
    int t  = id >> 6;              // 0..62
    int mt = (id >> 3) & 7;
    int nt = id & 7;

    int tid  = threadIdx.x;
    int wave = tid >> 6;
    int lane = tid & 63;
    int la = lane & 15;
    int lq = lane >> 4;
    int wr = (wave & 1) * 64;      // wave row offset
    int wc = (wave >> 1) * 64;     // wave col offset

    const int* Ag = (const int*)fh + ((size_t)t * GN + mt * 128) * 64;
    const int* Bg = (const int*)fh + ((size_t)(t + 1) * GN + nt * 128) * 64;

    #pragma unroll
    for (int i = 0; i < 8; ++i) {
        int L = i * 256 + tid;         // granule index in tile
        int row = L >> 4, colL = L & 15;
        int colG = colL ^ (row & 7);
        gload_lds16(Ag + row * 64 + colG * 4, &Atile[L * 4]);
        gload_lds16(Bg + row * 64 + colG * 4, &Btile[L * 4]);
    }
    __syncthreads();                   // includes vmcnt(0) drain

    f32x4 acc[4][4];
    #pragma unroll
    for (int at = 0; at < 4; ++at)
        #pragma unroll
        for (int ct = 0; ct < 4; ++ct) acc[at][ct] = (f32x4){0.f, 0.f, 0.f, 0.f};

    #pragma unroll
    for (int kc = 0; kc < 4; ++kc) {
        int sw = ((kc * 4 + lq) ^ (la & 7)) << 2;   // swizzled in-row int offset
        f16x8 af[4], bf[4];
        #pragma unroll
        for (int x = 0; x < 4; ++x) {
            af[x] = __builtin_bit_cast(f16x8, *(const int4*)&Atile[(wr + x * 16 + la) * 64 + sw]);
            bf[x] = __builtin_bit_cast(f16x8, *(const int4*)&Btile[(wc + x * 16 + la) * 64 + sw]);
        }
        #pragma unroll
        for (int at = 0; at < 4; ++at)
            #pragma unroll
            for (int ct = 0; ct < 4; ++ct)
                acc[at][ct] = __builtin_amdgcn_mfma_f32_16x16x32_f16(
                    af[at], bf[ct], acc[at][ct], 0, 0, 0);
    }

    // per-lane top-2 over this block's cols (C layout: col=la, row=lq*4+reg)
    float t1[16], t2[16]; int i1[16];
    #pragma unroll
    for (int s = 0; s < 16; ++s) { t1[s] = -3.4e38f; t2[s] = -3.4e38f; i1[s] = 0x7fffffff; }

    const float* rB = rnf + (size_t)(t + 1) * GN + nt * 128;
    #pragma unroll
    for (int ct = 0; ct < 4; ++ct) {               // ct ascending = n ascending
        int cloc = wc + ct * 16 + la;
        int n = nt * 128 + cloc;
        float rn = rB[cloc];
        #pragma unroll
        for (int at = 0; at < 4; ++at) {
            #pragma unroll
            for (int reg = 0; reg < 4; ++reg) {
                float v = acc[at][ct][reg] * rn;
                int s = at * 4 + reg;
                t2[s] = fmaxf(t2[s], fminf(v, t1[s]));   // med3(v,t1,t2)
                if (v > t1[s]) { t1[s] = v; i1[s] = n; }
            }
        }
    }

    // butterfly top-2 merge over the 16 la-lanes (same lq group)
    #pragma unroll
    for (int m = 1; m <= 8; m <<= 1) {
        #pragma unroll
        for (int s = 0; s < 16; ++s) {
            float o1 = __shfl_xor(t1[s], m);
            float o2 = __shfl_xor(t2[s], m);
            int   oi = __shfl_xor(i1[s], m);
            bool take = (o1 > t1[s]) || (o1 == t1[s] && oi < i1[s]);
            float nt2 = take ? fmaxf(o2, t1[s]) : fmaxf(t2[s], o1);
            if (take) { t1[s] = o1; i1[s] = oi; }
            t2[s] = nt2;
        }
    }

    // cross-wave merge (2 column halves) via overlay on Atile
    __syncthreads();                   // all tile reads done
    float* mv1 = (float*)Atile;        // [128][2]
    float* mv2 = mv1 + 256;
    int*   mi1 = (int*)(mv2 + 256);
    if (la == 0) {
        #pragma unroll
        for (int s = 0; s < 16; ++s) {
            int row = wr + (s >> 2) * 16 + lq * 4 + (s & 3);
            int idx = row * 2 + (wave >> 1);
            mv1[idx] = t1[s]; mv2[idx] = t2[s]; mi1[idx] = i1[s];
        }
    }
    __syncthreads();

    if (tid < 128) {
        float best = mv1[tid * 2], sec, bw2 = mv2[tid * 2];
        int bi = mi1[tid * 2];
        float v1 = mv1[tid * 2 + 1], v2 = mv2[tid * 2 + 1];
        int  ii = mi1[tid * 2 + 1];
        if (v1 > best || (v1 == best && ii < bi)) {
            sec = fmaxf(best, v2); best = v1; bi = ii;   // winner half 1
        } else {
            sec = fmaxf(v1, bw2);
        }
        float4 o; o.x = best; o.y = sec; o.z = __int_as_float(bi); o.w = 0.f;
        tws[((size_t)t * GN + mt * 128 + tid) * 8 + nt] = o;
    }
}

// ---------------------------------------------------------------------------
// Kernel 3: merge 8 colblock candidates per row; gap<TAU -> per-t rescue list.
// Emits nxt16 (ushort local col index in next group).
// ---------------------------------------------------------------------------
__global__ void kmerge(const float4* __restrict__ tws, unsigned short* __restrict__ nxt16,
                       int* __restrict__ rcnt, int* __restrict__ rlistT) {
    int idx = blockIdx.x * 256 + threadIdx.x;      // 0..64511
    int t = idx >> 10, grow = idx & 1023;
    const float4* e = tws + (size_t)idx * 8;
    float best = -3.4e38f, sec = -3.4e38f, bw2 = -3.4e38f;
    int bi = 0x7fffffff;
    #pragma unroll
    for (int nb = 0; nb < 8; ++nb) {               // nb ascending = n ascending
        float4 v = e[nb];
        int ii = __float_as_int(v.z);
        if (v.x > best || (v.x == best && ii < bi)) {
            sec = fmaxf(sec, best);
            best = v.x; bi = ii; bw2 = v.y;
        } else {
            sec = fmaxf(sec, v.x);
        }
    }
    sec = fmaxf(sec, bw2);
    if (best - sec < TAU) {
        int p = atomicAdd(&rcnt[t], 1);
        rlistT[t * 1024 + p] = grow;
    } else {
        nxt16[idx] = (unsigned short)bi;
    }
}

// ---------------------------------------------------------------------------
// Kernel 4: fp64 rescue, batched per t. Block = (t, quarter q); 512 threads;
// two threads share one B row (each holds a 64-float half in registers, read
// ONCE from HBM). Loops the t's rescue rows: A row staged to LDS, fp64 dot,
// block-reduce -> per-(t,q) partial argmax. Exact fp64 math/tie rules.
// ---------------------------------------------------------------------------
__global__ __launch_bounds__(512) void krescue(const float* __restrict__ feat,
                                               const double* __restrict__ rnd,
                                               const int* __restrict__ rcnt,
                                               const int* __restrict__ rlistT,
                                               double* __restrict__ pbv,
                                               int* __restrict__ pbi) {
    __shared__ float  arow[128];
    __shared__ double cv[256];
    __shared__ int    ci[256];
    int bid = blockIdx.x;               // t*4 + q
    int t = bid >> 2, q = bid & 3;
    int nr = rcnt[t];
    if (nr == 0) return;
    int tid = threadIdx.x;
    int h   = q * 256 + (tid >> 1);     // global B row within group t+1
    int par = tid & 1;                  // k-half: 0 -> [0,64), 1 -> [64,128)

    const float* Bp = feat + ((size_t)(t + 1) * GN + h) * DK + par * 64;
    float4 br[16];
    #pragma unroll
    for (int i = 0; i < 16; ++i) br[i] = *(const float4*)(Bp + i * 4);
    double rb = rnd[(t + 1) * GN + h];

    for (int ri = 0; ri < nr; ++ri) {
        __syncthreads();                // protect arow/cv from prev iteration
        int grow = rlistT[t * 1024 + ri];
        if (tid < 32)
            *(float4*)&arow[tid * 4] =
                *(const float4*)(feat + ((size_t)t * GN + grow) * DK + tid * 4);
        __syncthreads();

        const float* ap = arow + par * 64;
        double s = 0.0;
        #pragma unroll
        for (int i = 0; i < 16; ++i) {
            float4 b = br[i];
            s = fma((double)ap[i * 4 + 0], (double)b.x, s);
            s = fma((double)ap[i * 4 + 1], (double)b.y, s);
            s = fma((double)ap[i * 4 + 2], (double)b.z, s);
            s = fma((double)ap[i * 4 + 3], (double)b.w, s);
        }
        double so = __shfl_xor(s, 1);   // partner half (fp add commutative)
        double stot = (s + so) * rb;
        if (par == 0) { cv[tid >> 1] = stot; ci[tid >> 1] = h; }
        __syncthreads();

        if (tid < 64) {
            double bv = cv[tid]; int bi = ci[tid];
            #pragma unroll
            for (int j = 1; j < 4; ++j) {
                double v = cv[tid + j * 64]; int ii = ci[tid + j * 64];
                if (v > bv || (v == bv && ii < bi)) { bv = v; bi = ii; }
            }
            #pragma unroll
            for (int off = 32; off > 0; off >>= 1) {
                double ov = __shfl_down(bv, off);
                int    oi = __shfl_down(bi, off);
                if (ov > bv || (ov == bv && oi < bi)) { bv = ov; bi = oi; }
            }
            if (tid == 0) {
                pbv[(size_t)bid * 1024 + ri] = bv;
                pbi[(size_t)bid * 1024 + ri] = bi;
            }
        }
    }
}

// ---------------------------------------------------------------------------
// Kernel 4b: merge the 4 quarter partials per rescue row (q ascending).
// ---------------------------------------------------------------------------
__global__ void kfinal(const int* __restrict__ rcnt, const int* __restrict__ rlistT,
                       const double* __restrict__ pbv, const int* __restrict__ pbi,
                       unsigned short* __restrict__ nxt16) {
    int gid = blockIdx.x * 256 + threadIdx.x;      // 0..64511
    int t = gid >> 10, ri = gid & 1023;
    if (t >= TT - 1 || ri >= rcnt[t]) return;
    double bv = -1e300; int bi = 0x7fffffff;
    #pragma unroll
    for (int q = 0; q < 4; ++q) {
        double v  = pbv[(size_t)(t * 4 + q) * 1024 + ri];
        int    ii = pbi[(size_t)(t * 4 + q) * 1024 + ri];
        if (v > bv || (v == bv && ii < bi)) { bv = v; bi = ii; }
    }
    nxt16[t * GN + rlistT[t * 1024 + ri]] = (unsigned short)bi;
}

// ---------------------------------------------------------------------------
// Kernel 5: chain propagation, fully LDS-resident. Single block, 1024 thr.
// ---------------------------------------------------------------------------
__global__ __launch_bounds__(1024) void kgraph(const unsigned short* __restrict__ nxt16,
                                               int* __restrict__ chain_of) {
    __shared__ unsigned short ns[64 * 1024];   // 128 KB (row 63 unused pad)
    __shared__ int winner[2 * 1024];           // 8 KB double-buffer
    int g = threadIdx.x;                       // 0..1023

    #pragma unroll
    for (int i = 0; i < 8; ++i)
        gload_lds16((const char*)nxt16 + ((size_t)i * 1024 + g) * 16,
                    (char*)ns + ((size_t)i * 1024 + g) * 16);

    winner[g] = 0x7fffffff;
    chain_of[g] = g;                           // group 0: identity
    int mychain = g;
    __syncthreads();                           // drains the global_load_lds too

    for (int t = 0; t < TT - 1; ++t) {
        int* Wa = winner + (t & 1) * GN;
        int* Wb = winner + ((t + 1) & 1) * GN;
        int j = ns[t * GN + g];                // local index in group t+1
        atomicMin(&Wa[j], mychain);
        Wb[g] = 0x7fffffff;
        __syncthreads();
        int w = Wa[g];
        mychain = (w == 0x7fffffff) ? (((t + 1) << 10) | g) : w;
        ns[t * GN + g] = (unsigned short)mychain;   // recycle consumed slot
        __syncthreads();
    }

    for (int t = 0; t < TT - 1; ++t)
        chain_of[(t + 1) * GN + g] = ns[t * GN + g];
}

// ---------------------------------------------------------------------------
// Kernel 6: chain lengths by owner count (clen pre-zeroed via memsetAsync).
// ---------------------------------------------------------------------------
__global__ void kclen(const int* __restrict__ chain_of, int* __restrict__ clen) {
    int i = blockIdx.x * 256 + threadIdx.x;
    atomicAdd(&clen[chain_of[i]], 1);
}

// ---------------------------------------------------------------------------
// Kernel 7a: per-block (1024-elem, coalesced) exclusive scan of kept lengths.
// ---------------------------------------------------------------------------
__global__ __launch_bounds__(1024) void kseg(const int* __restrict__ chain_of,
                                             const int* __restrict__ clen,
                                             const int* __restrict__ minp,
                                             int* __restrict__ oloc,
                                             int* __restrict__ partial) {
    __shared__ int ps[1024];
    int b = blockIdx.x, tid = threadIdx.x;
    int i = b * 1024 + tid;
    int ml = *minp;
    int cl = clen[i];
    int v = (chain_of[i] == i && cl >= ml) ? cl : 0;
    ps[tid] = v;
    __syncthreads();
    for (int off = 1; off < 1024; off <<= 1) {
        int add = (tid >= off) ? ps[tid - off] : 0;
        __syncthreads();
        ps[tid] += add;
        __syncthreads();
    }
    oloc[i] = ps[tid] - v;              // exclusive within block
    if (tid == 1023) partial[b] = ps[tid];
}

// ---------------------------------------------------------------------------
// Kernel 7b: one wave scans the 64 block partials; emits pbase + total.
// ---------------------------------------------------------------------------
__global__ void kpart(const int* __restrict__ partial, int* __restrict__ pbase,
                      int* __restrict__ total) {
    int tid = threadIdx.x;              // 0..63
    int v = partial[tid];
    int acc = v;
    #pragma unroll
    for (int off = 1; off < 64; off <<= 1) {
        int o = __shfl_up(acc, off);
        if (tid >= off) acc += o;
    }
    pbase[tid] = acc - v;               // exclusive
    if (tid == 63) *total = acc;
}

// ---------------------------------------------------------------------------
// Kernel 8: zero only the non-kept tail of the output.
// ---------------------------------------------------------------------------
__global__ void kzero(const int* __restrict__ total, float* __restrict__ out) {
    long start = (long)(*total) * OUTC;
    long end   = (long)NN * OUTC;
    long gid   = (long)blockIdx.x * 256 + threadIdx.x;
    long stride = (long)gridDim.x * 256;
    for (long i = start + gid; i < end; i += stride) out[i] = 0.f;
}

// ---------------------------------------------------------------------------
// Kernel 9: scatter kept rows, one wave per node (4 nodes / 256-thr block).
// ---------------------------------------------------------------------------
__global__ void kscatter(const float* __restrict__ coor, const float* __restrict__ feat,
                         const int* __restrict__ chain_of, const int* __restrict__ clen,
                         const int* __restrict__ oloc, const int* __restrict__ pbase,
                         const int* __restrict__ minp, float* __restrict__ out) {
    int node = blockIdx.x * 4 + (threadIdx.x >> 6);
    int lane = threadIdx.x & 63;
    int s = chain_of[node];
    if (clen[s] < *minp) return;
    int row = oloc[s] + pbase[s >> 10] + (node >> 10) - (s >> 10);
    float* orow = out + (size_t)row * OUTC;
    const float* f = feat + (size_t)node * DK;
    if (lane < 3) orow[lane] = coor[(size_t)node * 3 + lane];
    orow[3 + lane]  = f[lane];
    orow[67 + lane] = f[64 + lane];
}

// ---------------------------------------------------------------------------
extern "C" void kernel_launch(void* const* d_in, const int* in_sizes, int n_in,
                              void* d_out, int out_size, void* d_ws, size_t ws_size,
                              hipStream_t stream) {
    const float* coor   = (const float*)d_in[0];   // [N,3]
    const float* feat   = (const float*)d_in[1];   // [N,128]
    const int*   minlen = (const int*)d_in[2];     // scalar
    float*       out    = (float*)d_out;           // [N,131] fp32

    char* ws = (char*)d_ws;
    double*         rnd      = (double*)(ws);                  // 512 KB
    float*          rnf      = (float*)(ws + 524288);          // 256 KB
    unsigned short* nxt16    = (unsigned short*)(ws + 786432); // 128 KB
    int*            chain_of = (int*)(ws + 917504);            // 256 KB
    int*            clen     = (int*)(ws + 1179648);           // 256 KB
    int*            oloc     = (int*)(ws + 1441792);           // 256 KB
    int*            total    = (int*)(ws + 1703936);
    int*            rcnt     = (int*)(ws + 1704192);           // 63 ints
    int*            partial  = (int*)(ws + 1704448);           // 256 B
    int*            pbase    = (int*)(ws + 1704704);           // 256 B
    int*            rlistT   = (int*)(ws + 1705216);           // 63*1024*4 = 252 KB
    unsigned*       fh       = (unsigned*)(ws + 2097152);      // 16 MB
    float4*         tws      = (float4*)(ws + 18874368);       // 8.25 MB
    // pbv/pbi overlay tws (tws is dead after kmerge)
    double*         pbv      = (double*)(ws + 18874368);       // 252*1024*8 ~ 2 MB
    int*            pbi      = (int*)(ws + 18874368 + 2064384);// ~1 MB

    hipMemsetAsync(rcnt, 0, 63 * 4, stream);
    hipMemsetAsync(clen, 0, (size_t)NN * 4, stream);

    kconv<<<NN / 4, 256, 0, stream>>>(feat, fh, rnf, rnd);

    ksim<<<63 * 64, 256, 0, stream>>>(fh, rnf, tws);

    kmerge<<<63 * GN / 256, 256, 0, stream>>>(tws, nxt16, rcnt, rlistT);
    krescue<<<63 * 4, 512, 0, stream>>>(feat, rnd, rcnt, rlistT, pbv, pbi);
    kfinal<<<63 * 4, 256, 0, stream>>>(rcnt, rlistT, pbv, pbi, nxt16);

    kgraph<<<1, GN, 0, stream>>>(nxt16, chain_of);
    kclen<<<NN / 256, 256, 0, stream>>>(chain_of, clen);
    kseg<<<64, 1024, 0, stream>>>(chain_of, clen, minlen, oloc, partial);
    kpart<<<1, 64, 0, stream>>>(partial, pbase, total);
    kzero<<<2048, 256, 0, stream>>>(total, out);
    kscatter<<<NN / 4, 256, 0, stream>>>(coor, feat, chain_of, clen, oloc, pbase,
                                         minlen, out);
}